// Round 6
// baseline (1506.420 us; speedup 1.0000x reference)
//
#include <hip/hip_runtime.h>

// CLDice loss, round 6: two erosion iterations fused per dispatch.
// With a_k = erode^k(img):
//   skel=0; for k=0..10: delta = relu(a_k - dilate(erode(a_k))); skel += delta*(1-skel)
// fused2 computes per z-plane: b=erode(a_k), d1=dilate(b), c=erode(b)=a_{k+2},
// d2=dilate(c); applies delta_k then delta_{k+1} to skel; writes a_{k+2}.
// Dispatches/field: fused1(k=0) + 4x fused2 + fused2<LAST>(k=9,10 with reduction).
// Shifted LDS layouts (img origin x0-4, b origin x0-2, c origin x0-1) make every
// 3-wide window = 2 aligned b128 reads. b stored twice: raw (erode view; OOB is
// naturally +inf) and masked -inf (dilate view). c double-buffered, read 1 step
// delayed => 2 barriers/z-step.
// Workspace floats: [sums:16][A:N][B:N][skel:N], N = 14,155,776 (~170 MB).

#define ZD 192
#define YD 192
#define XD 192
#define NB 2
constexpr int PLANE = YD * XD;
constexpr int VOL   = ZD * PLANE;
constexpr int NTOT  = NB * VOL;
#define PINF __builtin_inff()

__device__ __forceinline__ float4 vf4(float v) { return make_float4(v, v, v, v); }
__device__ __forceinline__ float4 vmin(float4 a, float4 b) {
    return make_float4(fminf(a.x, b.x), fminf(a.y, b.y), fminf(a.z, b.z), fminf(a.w, b.w));
}
__device__ __forceinline__ float4 vmax(float4 a, float4 b) {
    return make_float4(fmaxf(a.x, b.x), fmaxf(a.y, b.y), fmaxf(a.z, b.z), fmaxf(a.w, b.w));
}

// ---------------- k=0 single-step kernel (round-5 structure, K0 hardcoded) ----------------
template <bool F1>
__global__ __launch_bounds__(256)
void fused1_kernel(float* __restrict__ img_out,
                   float* __restrict__ skel,
                   const float* __restrict__ logits,
                   const int* __restrict__ targets)
{
    constexpr int YT = 16, ZCH = 12;
    constexpr int IH = YT + 4, IWQ = 18;
    constexpr int BH = YT + 2, BWQ = 17;
    constexpr int NIMGQ = IH * IWQ;          // 360
    constexpr int NBQ   = BH * BWQ;          // 306
    constexpr int STEPS = ZCH + 4;           // 16

    __shared__ float simg[2][NIMGQ * 4];
    __shared__ float sbp[NBQ * 4];

    const int tx = threadIdx.x, ty = threadIdx.y;   // (16,16)
    const int tid = ty * 16 + tx;
    const int x0 = (blockIdx.x % 3) * 64, y0 = (blockIdx.x / 3) * YT;
    const int z0 = blockIdx.y * ZCH;
    const int bb = blockIdx.z;
    float*       outb = img_out + (size_t)bb * VOL;
    float*       skb  = skel    + (size_t)bb * VOL;
    const float* lg0  = logits  + (size_t)(bb * 2) * VOL;
    const float* lg1  = lg0 + VOL;
    const int*   tgb  = targets + (size_t)bb * VOL;

    const int q1off = ((tid & 3) << 6) + (tid >> 2);

    int im_qi[2] = { tid, 256 + q1off };
    int im_goff[2]; bool im_ok[2], im_has[2];
    #pragma unroll
    for (int j = 0; j < 2; ++j) {
        const int qi = im_qi[j];
        const int r = qi / IWQ, c = qi - r * IWQ;
        const int gy = y0 - 2 + r, gxb = x0 - 4 + 4 * c;
        im_has[j] = (qi < NIMGQ);
        im_ok[j]  = im_has[j] && gy >= 0 && gy < YD && gxb >= 0 && gxb < XD;
        im_goff[j] = gy * XD + gxb;
    }
    int bqi[2]; bool bhas[2]; int brow[2], bcol[2]; float4 bmask[2];
    #pragma unroll
    for (int j = 0; j < 2; ++j) {
        const int qi = (j == 0) ? tid : 256 + q1off;
        bqi[j] = qi;
        bhas[j] = (qi < NBQ);
        const int r = qi / BWQ, c = qi - r * BWQ;
        brow[j] = r; bcol[j] = c;
        const int gy = y0 - 1 + r, gxb = x0 - 1 + 4 * c;
        const bool yv = (gy >= 0 && gy < YD);
        float4 m;
        m.x = (yv && gxb     >= 0 && gxb     < XD) ? PINF : -PINF;
        m.y = (yv && gxb + 1 >= 0 && gxb + 1 < XD) ? PINF : -PINF;
        m.z = (yv && gxb + 2 >= 0 && gxb + 2 < XD) ? PINF : -PINF;
        m.w = (yv && gxb + 3 >= 0 && gxb + 3 < XD) ? PINF : -PINF;
        bmask[j] = m;
    }

    auto loadq = [&](int zi, int j) -> float4 {
        float4 v = vf4(PINF);
        if (im_ok[j] && zi >= 0 && zi < ZD) {
            const size_t p = (size_t)zi * PLANE + im_goff[j];
            if constexpr (F1) {
                const int4 t = *(const int4*)(tgb + p);
                v = make_float4(t.x == 1 ? 1.f : 0.f, t.y == 1 ? 1.f : 0.f,
                                t.z == 1 ? 1.f : 0.f, t.w == 1 ? 1.f : 0.f);
            } else {
                const float4 a = *(const float4*)(lg0 + p);
                const float4 b = *(const float4*)(lg1 + p);
                v = make_float4(1.f / (1.f + __expf(a.x - b.x)),
                                1.f / (1.f + __expf(a.y - b.y)),
                                1.f / (1.f + __expf(a.z - b.z)),
                                1.f / (1.f + __expf(a.w - b.w)));
            }
        }
        return v;
    };
    auto s1_of = [&](const float* sp, int j) -> float4 {
        const float* p = sp + brow[j] * (IWQ * 4) + 4 * bcol[j];
        float4 Ar = *(const float4*)p;
        float4 Br = *(const float4*)(p + 4);
        Ar = vmin(Ar, vmin(*(const float4*)(p + IWQ * 4), *(const float4*)(p + IWQ * 8)));
        Br = vmin(Br, vmin(*(const float4*)(p + IWQ * 4 + 4), *(const float4*)(p + IWQ * 8 + 4)));
        const float az = Ar.z, aw = Ar.w;
        const float t1 = fminf(az, aw);
        const float t2 = fminf(Br.x, Br.y);
        float4 m;
        m.x = fminf(Ar.y, t1);
        m.y = fminf(fminf(az, aw), Br.x);
        m.z = fminf(aw, t2);
        m.w = fminf(t2, Br.z);
        (void)t1;
        return m;
    };

    float4 p2a = vf4(PINF), p1a = vf4(PINF);
    float4 p2b = vf4(PINF), p1b = vf4(PINF);
    float4 s2p1 = vf4(-PINF), s2p2 = vf4(-PINF);
    float4 icp1 = vf4(0.f), icp2 = vf4(0.f), bcp1 = vf4(0.f);

    float4 ca0 = loadq(z0 - 2, 0);
    float4 ca1 = loadq(z0 - 2, 1);

    #pragma unroll 2
    for (int s = 0; s < STEPS; ++s) {
        const int zi = z0 - 2 + s;
        float* sp = simg[s & 1];
        *(float4*)(sp + 4 * im_qi[0]) = ca0;
        if (im_has[1]) *(float4*)(sp + 4 * im_qi[1]) = ca1;
        if (s + 1 < STEPS) { ca0 = loadq(zi + 1, 0); ca1 = loadq(zi + 1, 1); }
        __syncthreads();
        const int zb = zi - 1;
        const bool zbv = (s >= 2) && (zb >= 0) && (zb < ZD);
        {
            const float4 cur = s1_of(sp, 0);
            if (zbv) {
                float4 b = vmin(vmin(p2a, p1a), cur);
                *(float4*)(sbp + 4 * bqi[0]) = vmin(b, bmask[0]);
            }
            p2a = p1a; p1a = cur;
        }
        if (bhas[1]) {
            const float4 cur = s1_of(sp, 1);
            if (zbv) {
                float4 b = vmin(vmin(p2b, p1b), cur);
                *(float4*)(sbp + 4 * bqi[1]) = vmin(b, bmask[1]);
            }
            p2b = p1b; p1b = cur;
        }
        const float4 icq = *(const float4*)(sp + (ty + 2) * (IWQ * 4) + 4 * (tx + 1));
        __syncthreads();
        float4 s2n = vf4(-PINF), bcq = vf4(0.f);
        if (zbv) {
            const float* p = sbp + (ty * BWQ + tx) * 4;
            const float4 U0 = *(const float4*)p;
            const float4 V0 = *(const float4*)(p + 4);
            const float4 U1 = *(const float4*)(p + BWQ * 4);
            const float4 V1 = *(const float4*)(p + BWQ * 4 + 4);
            const float4 U2 = *(const float4*)(p + BWQ * 8);
            const float4 V2 = *(const float4*)(p + BWQ * 8 + 4);
            bcq = make_float4(U1.y, U1.z, U1.w, V1.x);
            const float4 Ur = vmax(U0, vmax(U1, U2));
            const float vx = fmaxf(V0.x, fmaxf(V1.x, V2.x));
            const float vy = fmaxf(V0.y, fmaxf(V1.y, V2.y));
            const float t1 = fmaxf(Ur.y, Ur.z);
            const float t2 = fmaxf(Ur.w, vx);
            s2n.x = fmaxf(Ur.x, t1);
            s2n.y = fmaxf(t1, Ur.w);
            s2n.z = fmaxf(Ur.z, t2);
            s2n.w = fmaxf(t2, vy);
        }
        if (s >= 4) {
            const int zo = zi - 2;
            const float4 d = vmax(s2p2, vmax(s2p1, s2n));
            float4 dl;
            dl.x = fmaxf(icp2.x - d.x, 0.f);
            dl.y = fmaxf(icp2.y - d.y, 0.f);
            dl.z = fmaxf(icp2.z - d.z, 0.f);
            dl.w = fmaxf(icp2.w - d.w, 0.f);
            const size_t idx = (size_t)zo * PLANE + (size_t)(y0 + ty) * XD + (x0 + 4 * tx);
            *(float4*)(skb + idx)  = dl;      // skel = delta (k=0)
            *(float4*)(outb + idx) = bcp1;    // a1
        }
        s2p2 = s2p1; s2p1 = s2n;
        icp2 = icp1; icp1 = icq;
        bcp1 = bcq;
    }
}

// ---------------- double-step kernel ----------------
template <bool LAST, bool F1>
__global__ __launch_bounds__(192)
void fused2_kernel(const float* __restrict__ img_in,
                   float* __restrict__ img_out,
                   float* __restrict__ skel,
                   const float* __restrict__ logits,
                   const int* __restrict__ targets,
                   float* __restrict__ sums)
{
    constexpr int YT = 12, ZCH = 12;
    constexpr int IWQ = 18, IH = 18;         // img: rows y0-3..y0+14, quads x0-4..x0+67
    constexpr int BWQ = 17, BH = 16;         // b:   rows y0-2..y0+13, origin x0-2
    constexpr int CWQ = 17, CH = 14;         // c:   rows y0-1..y0+12, origin x0-1
    constexpr int NIMG = IH * IWQ;           // 324
    constexpr int NBQ  = BH * BWQ;           // 272
    constexpr int NCQ  = CH * CWQ;           // 238
    constexpr int STEPS = ZCH + 7;           // 19

    __shared__ float simg[2][NIMG * 4];
    __shared__ float sbx[NBQ * 4 + 4];       // b, -inf at invalid (dilate view)
    __shared__ float sbn[NBQ * 4 + 4];       // b raw (+inf at invalid naturally; erode view)
    __shared__ float scc[2][NCQ * 4];        // c, -inf at invalid (dilate view)
    __shared__ float red[3][2];

    const int tx = threadIdx.x, ty = threadIdx.y;   // (16,12)
    const int tid = ty * 16 + tx;
    const int x0 = (blockIdx.x % 3) * 64, y0 = (blockIdx.x / 3) * YT;
    const int z0 = blockIdx.y * ZCH;
    const int bb = blockIdx.z;
    const float* inb  = img_in  + (size_t)bb * VOL;
    float*       outb = img_out + (size_t)bb * VOL;
    float*       skb  = skel    + (size_t)bb * VOL;
    const float* lg0  = logits  + (size_t)(bb * 2) * VOL;
    const float* lg1  = lg0 + VOL;
    const int*   tgb  = targets + (size_t)bb * VOL;

    // img chunks
    const bool ihas1 = (tid + 192) < NIMG;           // tid < 132
    int ig[2]; bool iok[2];
    #pragma unroll
    for (int j = 0; j < 2; ++j) {
        const int qi = tid + j * 192;
        const int r = qi / IWQ, c = qi - r * IWQ;
        const int gy = y0 - 3 + r, gx = x0 - 4 + 4 * c;
        iok[j] = (j == 0 || ihas1) && gy >= 0 && gy < YD && gx >= 0 && gx < XD;
        ig[j] = gy * XD + gx;
    }
    // b chunks
    const bool bhas1 = (tid + 192) < NBQ;            // tid < 80
    int bimg[2], bwr[2]; float4 Mb[2];
    #pragma unroll
    for (int j = 0; j < 2; ++j) {
        const int qi = tid + j * 192;
        const int r = qi / BWQ, c = qi - r * BWQ;
        bimg[j] = (r * IWQ + c) * 4;
        bwr[j]  = qi * 4;
        const int gy = y0 - 2 + r, gx = x0 - 2 + 4 * c;
        const bool yv = (gy >= 0 && gy < YD);
        float4 m;
        m.x = (yv && gx     >= 0 && gx     < XD) ? PINF : -PINF;
        m.y = (yv && gx + 1 >= 0 && gx + 1 < XD) ? PINF : -PINF;
        m.z = (yv && gx + 2 >= 0 && gx + 2 < XD) ? PINF : -PINF;
        m.w = (yv && gx + 3 >= 0 && gx + 3 < XD) ? PINF : -PINF;
        Mb[j] = m;
    }
    // c chunks
    const bool chas1 = (tid + 192) < NCQ;            // tid < 46
    int cbr[2], cwr[2]; float4 Mc[2];
    #pragma unroll
    for (int j = 0; j < 2; ++j) {
        const int qi = tid + j * 192;
        const int r = qi / CWQ, c = qi - r * CWQ;
        cbr[j] = (r * BWQ + c) * 4;
        cwr[j] = qi * 4;
        const int gy = y0 - 1 + r, gx = x0 - 1 + 4 * c;
        const bool yv = (gy >= 0 && gy < YD);
        float4 m;
        m.x = (yv && gx     >= 0 && gx     < XD) ? PINF : -PINF;
        m.y = (yv && gx + 1 >= 0 && gx + 1 < XD) ? PINF : -PINF;
        m.z = (yv && gx + 2 >= 0 && gx + 2 < XD) ? PINF : -PINF;
        m.w = (yv && gx + 3 >= 0 && gx + 3 < XD) ? PINF : -PINF;
        Mc[j] = m;
    }

    auto loadq = [&](int zi, int j) -> float4 {
        if (zi < 0 || zi >= ZD || !iok[j]) return vf4(PINF);
        return *(const float4*)(inb + (size_t)zi * PLANE + ig[j]);
    };
    // erode xy-min at b slot j from img plane sp
    auto s1_of = [&](const float* sp, int j) -> float4 {
        const float* p = sp + bimg[j];
        float4 Ar = *(const float4*)p;
        float4 Br = *(const float4*)(p + 4);
        Ar = vmin(Ar, vmin(*(const float4*)(p + IWQ * 4), *(const float4*)(p + IWQ * 8)));
        Br = vmin(Br, vmin(*(const float4*)(p + IWQ * 4 + 4), *(const float4*)(p + IWQ * 8 + 4)));
        const float t1 = fminf(Ar.z, Ar.w);
        const float t2 = fminf(Br.x, Br.y);
        return make_float4(fminf(Ar.y, t1), fminf(t1, Br.x), fminf(Ar.w, t2), fminf(t2, Br.z));
    };
    // erode xy-min at c slot j from raw-b plane
    auto s3_of = [&](int j) -> float4 {
        const float* p = sbn + cbr[j];
        float4 Ur = *(const float4*)p;
        float4 Vr = *(const float4*)(p + 4);
        Ur = vmin(Ur, vmin(*(const float4*)(p + BWQ * 4), *(const float4*)(p + BWQ * 8)));
        Vr = vmin(Vr, vmin(*(const float4*)(p + BWQ * 4 + 4), *(const float4*)(p + BWQ * 8 + 4)));
        const float u = fminf(Ur.y, Ur.z);
        const float v = fminf(Ur.w, Vr.x);
        return make_float4(fminf(Ur.x, u), fminf(u, Ur.w), fminf(Ur.z, v), fminf(v, Vr.y));
    };

    float4 s1p1[2] = { vf4(PINF), vf4(PINF) }, s1p2[2] = { vf4(PINF), vf4(PINF) };
    float4 s3p1[2] = { vf4(PINF), vf4(PINF) }, s3p2[2] = { vf4(PINF), vf4(PINF) };
    float4 s2p1 = vf4(-PINF), s2p2 = vf4(-PINF), s2p3 = vf4(-PINF), s2p4 = vf4(-PINF);
    float4 s4p1 = vf4(-PINF), s4p2 = vf4(-PINF);
    float4 icp1 = vf4(0.f), icp2 = vf4(0.f), icp3 = vf4(0.f), icp4 = vf4(0.f);
    float4 bcp1 = vf4(0.f), bcp2 = vf4(0.f), bcp3 = vf4(0.f);
    float4 ccp1 = vf4(0.f);
    float sd = 0.f, ss = 0.f;

    float4 ca0 = loadq(z0 - 3, 0), ca1 = loadq(z0 - 3, 1);

    #pragma unroll 1
    for (int s = 0; s < STEPS; ++s) {
        const int zi = z0 - 3 + s;
        float* sp = simg[s & 1];
        if (s <= 17) {
            *(float4*)(sp + tid * 4) = ca0;
            if (ihas1) *(float4*)(sp + (tid + 192) * 4) = ca1;
            if (s <= 16) { ca0 = loadq(zi + 1, 0); ca1 = loadq(zi + 1, 1); }
        }
        __syncthreads();                                // B1: img plane ready
        const int zb = zi - 1;
        const bool zbv = (zb >= 0) && (zb < ZD);
        float4 icq = vf4(0.f);
        if (s <= 17) {
            {
                const float4 cur = s1_of(sp, 0);
                if (zbv) {
                    const float4 b = vmin(vmin(s1p2[0], s1p1[0]), cur);
                    *(float4*)(sbn + bwr[0]) = b;
                    *(float4*)(sbx + bwr[0]) = vmin(b, Mb[0]);
                }
                s1p2[0] = s1p1[0]; s1p1[0] = cur;
            }
            if (bhas1) {
                const float4 cur = s1_of(sp, 1);
                if (zbv) {
                    const float4 b = vmin(vmin(s1p2[1], s1p1[1]), cur);
                    *(float4*)(sbn + bwr[1]) = b;
                    *(float4*)(sbx + bwr[1]) = vmin(b, Mb[1]);
                }
                s1p2[1] = s1p1[1]; s1p1[1] = cur;
            }
            icq = *(const float4*)(sp + ((ty + 3) * IWQ + tx + 1) * 4);
        }
        __syncthreads();                                // B2: b planes ready
        // ---- stage C: d1 parts + second erode + c write
        float4 s2cur = vf4(-PINF), bcq = vf4(0.f);
        float4 s3c0 = vf4(PINF), s3c1 = vf4(PINF);
        if (s >= 2 && s <= 17 && zbv) {
            const float* p = sbx + ((ty + 1) * BWQ + tx) * 4;
            const float4 U0 = *(const float4*)p;
            const float4 V0 = *(const float4*)(p + 4);
            const float4 U1 = *(const float4*)(p + BWQ * 4);
            const float4 V1 = *(const float4*)(p + BWQ * 4 + 4);
            const float4 U2 = *(const float4*)(p + BWQ * 8);
            const float4 V2 = *(const float4*)(p + BWQ * 8 + 4);
            bcq = make_float4(U1.z, U1.w, V1.x, V1.y);
            const float4 Ur = vmax(U0, vmax(U1, U2));
            const float4 Vr = vmax(V0, vmax(V1, V2));
            const float u = fmaxf(Ur.z, Ur.w);
            const float v = fmaxf(Vr.x, Vr.y);
            s2cur = make_float4(fmaxf(Ur.y, u), fmaxf(u, Vr.x), fmaxf(Ur.w, v), fmaxf(v, Vr.z));
            s3c0 = s3_of(0);
            if (chas1) s3c1 = s3_of(1);
        }
        const int zc = zi - 2;
        if (s >= 2 && s <= 17 && zc >= 0 && zc < ZD) {
            float* cw = scc[s & 1];
            *(float4*)(cw + cwr[0]) = vmin(vmin(vmin(s3p2[0], s3p1[0]), s3c0), Mc[0]);
            if (chas1)
                *(float4*)(cw + cwr[1]) = vmin(vmin(vmin(s3p2[1], s3p1[1]), s3c1), Mc[1]);
        }
        s3p2[0] = s3p1[0]; s3p1[0] = s3c0;
        s3p2[1] = s3p1[1]; s3p1[1] = s3c1;
        // ---- stage D: dilate of c (previous step's plane)
        float4 s4cur = vf4(-PINF), ccq = vf4(0.f);
        const int zcp = zi - 3;
        if (s >= 5 && zcp >= 0 && zcp < ZD) {
            const float* p = scc[(s - 1) & 1] + (ty * CWQ + tx) * 4;
            const float4 U0 = *(const float4*)p;
            const float4 V0 = *(const float4*)(p + 4);
            const float4 U1 = *(const float4*)(p + CWQ * 4);
            const float4 V1 = *(const float4*)(p + CWQ * 4 + 4);
            const float4 U2 = *(const float4*)(p + CWQ * 8);
            const float4 V2 = *(const float4*)(p + CWQ * 8 + 4);
            ccq = make_float4(U1.y, U1.z, U1.w, V1.x);
            const float4 Ur = vmax(U0, vmax(U1, U2));
            const float4 Vr = vmax(V0, vmax(V1, V2));
            const float u = fmaxf(Ur.y, Ur.z);
            const float v = fmaxf(Ur.w, Vr.x);
            s4cur = make_float4(fmaxf(Ur.x, u), fmaxf(u, Ur.w), fmaxf(Ur.z, v), fmaxf(v, Vr.y));
        }
        // ---- emit zo = zi-4
        if (s >= 7) {
            const int zo = zi - 4;
            const float4 d1 = vmax(s2p2, vmax(s2p3, s2p4));
            const float4 d2 = vmax(s4cur, vmax(s4p1, s4p2));
            float4 dl0, dl1;
            dl0.x = fmaxf(icp4.x - d1.x, 0.f);
            dl0.y = fmaxf(icp4.y - d1.y, 0.f);
            dl0.z = fmaxf(icp4.z - d1.z, 0.f);
            dl0.w = fmaxf(icp4.w - d1.w, 0.f);
            dl1.x = fmaxf(bcp3.x - d2.x, 0.f);
            dl1.y = fmaxf(bcp3.y - d2.y, 0.f);
            dl1.z = fmaxf(bcp3.z - d2.z, 0.f);
            dl1.w = fmaxf(bcp3.w - d2.w, 0.f);
            const size_t idx = (size_t)zo * PLANE + (size_t)(y0 + ty) * XD + (x0 + 4 * tx);
            const float4 sk = *(const float4*)(skb + idx);
            float4 sm, sn;
            sm.x = sk.x + dl0.x * (1.f - sk.x);
            sm.y = sk.y + dl0.y * (1.f - sk.y);
            sm.z = sk.z + dl0.z * (1.f - sk.z);
            sm.w = sk.w + dl0.w * (1.f - sk.w);
            sn.x = sm.x + dl1.x * (1.f - sm.x);
            sn.y = sm.y + dl1.y * (1.f - sm.y);
            sn.z = sm.z + dl1.z * (1.f - sm.z);
            sn.w = sm.w + dl1.w * (1.f - sm.w);
            if constexpr (!LAST) {
                *(float4*)(skb + idx)  = sn;
                *(float4*)(outb + idx) = ccp1;    // a_{k+2}
            } else {
                float4 w;
                if constexpr (F1) {
                    const float4 a = *(const float4*)(lg0 + idx);
                    const float4 b = *(const float4*)(lg1 + idx);
                    w = make_float4(1.f / (1.f + __expf(a.x - b.x)),
                                    1.f / (1.f + __expf(a.y - b.y)),
                                    1.f / (1.f + __expf(a.z - b.z)),
                                    1.f / (1.f + __expf(a.w - b.w)));
                } else {
                    const int4 t = *(const int4*)(tgb + idx);
                    w = make_float4(t.x == 1 ? 1.f : 0.f, t.y == 1 ? 1.f : 0.f,
                                    t.z == 1 ? 1.f : 0.f, t.w == 1 ? 1.f : 0.f);
                }
                sd += sn.x * w.x + sn.y * w.y + sn.z * w.z + sn.w * w.w;
                ss += sn.x + sn.y + sn.z + sn.w;
            }
        }
        // ring shifts
        s2p4 = s2p3; s2p3 = s2p2; s2p2 = s2p1; s2p1 = s2cur;
        s4p2 = s4p1; s4p1 = s4cur;
        icp4 = icp3; icp3 = icp2; icp2 = icp1; icp1 = icq;
        bcp3 = bcp2; bcp2 = bcp1; bcp1 = bcq;
        ccp1 = ccq;
    }

    if constexpr (LAST) {
        #pragma unroll
        for (int o = 32; o; o >>= 1) {
            sd += __shfl_down(sd, o, 64);
            ss += __shfl_down(ss, o, 64);
        }
        const int w = tid >> 6;
        if ((tid & 63) == 0) { red[w][0] = sd; red[w][1] = ss; }
        __syncthreads();
        if (tid == 0) {
            const float a = red[0][0] + red[1][0] + red[2][0];
            const float b = red[0][1] + red[1][1] + red[2][1];
            const int f = F1 ? 1 : 0;
            atomicAdd(&sums[2 * f + 0], a);
            atomicAdd(&sums[2 * f + 1], b);
        }
    }
}

__global__ void final_kernel(const float* __restrict__ sums, float* __restrict__ out)
{
    float tprec = (sums[0] + 1.f) / (sums[1] + 1.f);
    float tsens = (sums[2] + 1.f) / (sums[3] + 1.f);
    float cl = 2.f * tprec * tsens / (tprec + tsens + 1e-7f);
    out[0] = 1.f - cl;
}

extern "C" void kernel_launch(void* const* d_in, const int* in_sizes, int n_in,
                              void* d_out, int out_size, void* d_ws, size_t ws_size,
                              hipStream_t stream)
{
    const float* logits  = (const float*)d_in[0];
    const int*   targets = (const int*)d_in[1];
    float* out  = (float*)d_out;

    float* sums = (float*)d_ws;
    float* A    = sums + 16;
    float* B    = A + NTOT;
    float* SK   = B + NTOT;

    hipMemsetAsync(sums, 0, 16 * sizeof(float), stream);

    dim3 g1(3 * (YD / 16), ZD / 12, NB);   // (36,16,2), 256-thread blocks
    dim3 b1(16, 16, 1);
    dim3 g2(3 * (YD / 12), ZD / 12, NB);   // (48,16,2) = 1536 blocks, 192-thread
    dim3 b2(16, 12, 1);

    for (int field = 0; field < 2; ++field) {
        // k = 0 (single): writes a1 -> A, skel = delta0
        if (field) fused1_kernel<true ><<<g1, b1, 0, stream>>>(A, SK, logits, targets);
        else       fused1_kernel<false><<<g1, b1, 0, stream>>>(A, SK, logits, targets);
        // doubles: (1,2) A->B, (3,4) B->A, (5,6) A->B, (7,8) B->A
        const float* ins[4]  = { A, B, A, B };
        float*       outs[4] = { B, A, B, A };
        for (int p = 0; p < 4; ++p) {
            if (field) fused2_kernel<false, true ><<<g2, b2, 0, stream>>>(ins[p], outs[p], SK, logits, targets, sums);
            else       fused2_kernel<false, false><<<g2, b2, 0, stream>>>(ins[p], outs[p], SK, logits, targets, sums);
        }
        // (9,10) LAST: reads A (a9) + skel, reduces
        if (field) fused2_kernel<true, true ><<<g2, b2, 0, stream>>>(A, B, SK, logits, targets, sums);
        else       fused2_kernel<true, false><<<g2, b2, 0, stream>>>(A, B, SK, logits, targets, sums);
    }
    final_kernel<<<1, 1, 0, stream>>>(sums, out);
}

// Round 7
// 1195.413 us; speedup vs baseline: 1.2602x; 1.2602x over previous
//
#include <hip/hip_runtime.h>
#include <hip/hip_fp16.h>

// CLDice loss, round 7: round-5 structure + fp16 inter-iteration state +
// both fields/batches in one grid.
// Identity: with a_k = erode^k(img):
//   skel=0; for k=0..10: delta = relu(a_k - dilate(erode(a_k))); skel += delta*(1-skel)
// Erode/dilate are pure selections => once a0 is rounded to fp16, every a_k is an
// EXACT min/max over that fp16 lattice (gt field is exactly 0/1). Only skel's
// store rounds (~5e-4 rel, unbiased) -> final scalar error ~1e-3 << 1e-2.
// fp16 state A+B+SK = 170 MB fits the 256 MB Infinity Cache -> k>=1 dispatches
// run mostly out of L3.
// MODE 0: k=0 (a0 built inline from logits/targets, skel=delta0)
// MODE 1: mid (read a_k+skel, write a_{k+1}+skel)
// MODE 2: last (k=10; reduce instead of writing)
// Workspace: [sums:16 f32][A][B][SK], each 4*VOL fp16 (~56.6 MB) => ~170 MB.

#define ZD 192
#define YD 192
#define XD 192
constexpr int PLANE = YD * XD;
constexpr int VOL   = ZD * PLANE;        // one (batch) volume
constexpr int NVOL4 = 4 * VOL;           // 2 fields x 2 batches

constexpr int XT = 64, YT = 16, ZCH = 16;
constexpr int IWQ = 18, SIW = 19;        // img real quads / padded LDS stride (quads)
constexpr int IH  = 20;                  // rows y0-2..y0+17
constexpr int NIMGQ = IH * IWQ;          // 360
constexpr int BWQ = 17, BH = 18;         // b plane: origin x0-1, rows y0-1..y0+16
constexpr int NBQ  = BH * BWQ;           // 306
constexpr int STEPS = ZCH + 4;           // 20
#define PINF __builtin_inff()

__device__ __forceinline__ float4 vf4(float v) { return make_float4(v, v, v, v); }
__device__ __forceinline__ float4 vmin(float4 a, float4 b) {
    return make_float4(fminf(a.x, b.x), fminf(a.y, b.y), fminf(a.z, b.z), fminf(a.w, b.w));
}
__device__ __forceinline__ float4 vmax(float4 a, float4 b) {
    return make_float4(fmaxf(a.x, b.x), fmaxf(a.y, b.y), fmaxf(a.z, b.z), fmaxf(a.w, b.w));
}
__device__ __forceinline__ float4 ldh4(const __half* p) {
    const __half2* q = (const __half2*)p;
    const float2 lo = __half22float2(q[0]);
    const float2 hi = __half22float2(q[1]);
    return make_float4(lo.x, lo.y, hi.x, hi.y);
}
__device__ __forceinline__ void sth4(__half* p, float4 v) {
    __half2* q = (__half2*)p;
    q[0] = __floats2half2_rn(v.x, v.y);
    q[1] = __floats2half2_rn(v.z, v.w);
}

template <int MODE>   // 0=k0, 1=mid, 2=last
__global__ __launch_bounds__(256)
void fused_kernel(const __half* __restrict__ a_in,
                  __half* __restrict__ a_out,
                  __half* __restrict__ skel,
                  const float* __restrict__ logits,
                  const int* __restrict__ targets,
                  float* __restrict__ sums)
{
    __shared__ float simg[2][IH * SIW * 4];
    __shared__ float sbp[NBQ * 4 + 8];
    __shared__ float red[4][2];

    const int tx = threadIdx.x, ty = threadIdx.y;   // (16,16)
    const int tid = ty * 16 + tx;
    const int x0 = (blockIdx.x % 3) * XT, y0 = (blockIdx.x / 3) * YT;
    const int z0 = blockIdx.y * ZCH;
    const int zf = blockIdx.z;                      // 0..3
    const int bb = zf & 1, field = zf >> 1;
    const size_t voff = (size_t)zf * VOL;
    const __half* inb  = a_in  + voff;
    __half*       outb = a_out + voff;
    __half*       skb  = skel  + voff;
    const float* lg0 = logits + (size_t)(bb * 2) * VOL;
    const float* lg1 = lg0 + VOL;
    const int*   tgb = targets + (size_t)bb * VOL;

    const int q1off = ((tid & 3) << 6) + (tid >> 2);  // balanced 2nd-chunk id

    // ---- img chunks: qi -> row r=qi/18, col c=qi%18; LDS addr (r*SIW+c)*4
    int im_qi[2] = { tid, 256 + q1off };
    int im_addr[2], im_goff[2]; bool im_ok[2], im_has[2];
    #pragma unroll
    for (int j = 0; j < 2; ++j) {
        const int qi = im_qi[j];
        const int r = qi / IWQ, c = qi - r * IWQ;
        const int gy = y0 - 2 + r, gxb = x0 - 4 + 4 * c;
        im_has[j] = (qi < NIMGQ);
        im_ok[j]  = im_has[j] && gy >= 0 && gy < YD && gxb >= 0 && gxb < XD;
        im_goff[j] = gy * XD + gxb;
        im_addr[j] = (r * SIW + c) * 4;
    }
    // ---- b chunks: qi -> (r=qi/17, c=qi%17); covers (y0-1+r, x0-1+4c)
    int bqi[2], brow[2], bcol[2]; bool bhas[2]; float4 bmask[2];
    #pragma unroll
    for (int j = 0; j < 2; ++j) {
        const int qi = (j == 0) ? tid : 256 + q1off;
        bqi[j] = qi;
        bhas[j] = (qi < NBQ);
        const int r = qi / BWQ, c = qi - r * BWQ;
        brow[j] = r; bcol[j] = c;
        const int gy = y0 - 1 + r, gxb = x0 - 1 + 4 * c;
        const bool yv = (gy >= 0 && gy < YD);
        float4 m;
        m.x = (yv && gxb     >= 0 && gxb     < XD) ? PINF : -PINF;
        m.y = (yv && gxb + 1 >= 0 && gxb + 1 < XD) ? PINF : -PINF;
        m.z = (yv && gxb + 2 >= 0 && gxb + 2 < XD) ? PINF : -PINF;
        m.w = (yv && gxb + 3 >= 0 && gxb + 3 < XD) ? PINF : -PINF;
        bmask[j] = m;
    }

    auto loadq = [&](int zi, int j) -> float4 {
        if (zi < 0 || zi >= ZD || !im_ok[j]) return vf4(PINF);
        const size_t p = (size_t)zi * PLANE + im_goff[j];
        if constexpr (MODE == 0) {
            if (field) {
                const int4 t = *(const int4*)(tgb + p);
                return make_float4(t.x == 1 ? 1.f : 0.f, t.y == 1 ? 1.f : 0.f,
                                   t.z == 1 ? 1.f : 0.f, t.w == 1 ? 1.f : 0.f);
            } else {
                const float4 a = *(const float4*)(lg0 + p);
                const float4 b = *(const float4*)(lg1 + p);
                return make_float4(1.f / (1.f + __expf(a.x - b.x)),
                                   1.f / (1.f + __expf(a.y - b.y)),
                                   1.f / (1.f + __expf(a.z - b.z)),
                                   1.f / (1.f + __expf(a.w - b.w)));
            }
        } else {
            return ldh4(inb + p);
        }
    };

    // erode xy-min for b slot j from img plane sp (verified round-5 windows)
    auto s1_of = [&](const float* sp, int j) -> float4 {
        const float* p = sp + brow[j] * (SIW * 4) + 4 * bcol[j];
        const float4 A0 = *(const float4*)p;
        const float4 B0 = *(const float4*)(p + 4);
        const float4 A1 = *(const float4*)(p + SIW * 4);
        const float4 B1 = *(const float4*)(p + SIW * 4 + 4);
        const float4 A2 = *(const float4*)(p + SIW * 8);
        const float4 B2 = *(const float4*)(p + SIW * 8 + 4);
        const float az = fminf(A0.z, fminf(A1.z, A2.z));
        const float aw = fminf(A0.w, fminf(A1.w, A2.w));
        const float4 Br = vmin(B0, vmin(B1, B2));
        const float t1 = fminf(aw, Br.x);
        const float t2 = fminf(Br.y, Br.z);
        return make_float4(fminf(az, t1), fminf(t1, Br.y),
                           fminf(Br.x, t2), fminf(t2, Br.w));
    };

    float4 p2a = vf4(PINF), p1a = vf4(PINF);   // s1 z-ring chunk0
    float4 p2b = vf4(PINF), p1b = vf4(PINF);   // s1 z-ring chunk1
    float4 s2p1 = vf4(-PINF), s2p2 = vf4(-PINF);
    float4 icp1 = vf4(0.f), icp2 = vf4(0.f), bcp1 = vf4(0.f);
    float sd = 0.f, ss = 0.f;

    float4 ca0 = loadq(z0 - 2, 0);
    float4 ca1 = loadq(z0 - 2, 1);

    #pragma unroll 2
    for (int s = 0; s < STEPS; ++s) {
        const int zi = z0 - 2 + s;
        float* sp = simg[s & 1];
        *(float4*)(sp + im_addr[0]) = ca0;
        if (im_has[1]) *(float4*)(sp + im_addr[1]) = ca1;
        if (s + 1 < STEPS) { ca0 = loadq(zi + 1, 0); ca1 = loadq(zi + 1, 1); }
        __syncthreads();                        // B1: simg[s&1] ready
        const int zb = zi - 1;
        const bool zbv = (s >= 2) && (zb >= 0) && (zb < ZD);
        {
            const float4 cur = s1_of(sp, 0);
            if (zbv) {
                float4 b = vmin(vmin(p2a, p1a), cur);
                *(float4*)(sbp + 4 * bqi[0]) = vmin(b, bmask[0]);
            }
            p2a = p1a; p1a = cur;
        }
        if (bhas[1]) {
            const float4 cur = s1_of(sp, 1);
            if (zbv) {
                float4 b = vmin(vmin(p2b, p1b), cur);
                *(float4*)(sbp + 4 * bqi[1]) = vmin(b, bmask[1]);
            }
            p2b = p1b; p1b = cur;
        }
        const float4 icq = *(const float4*)(sp + ((ty + 2) * SIW + tx + 1) * 4);
        __syncthreads();                        // B2: b plane ready
        // dilate xy-max at output quad (tx,ty) from b rows ty..ty+2, quads tx,tx+1
        float4 s2n = vf4(-PINF), bcq = vf4(0.f);
        if (zbv) {
            const float* p = sbp + (ty * BWQ + tx) * 4;
            const float4 U0 = *(const float4*)p;
            const float4 V0 = *(const float4*)(p + 4);
            const float4 U1 = *(const float4*)(p + BWQ * 4);
            const float4 V1 = *(const float4*)(p + BWQ * 4 + 4);
            const float4 U2 = *(const float4*)(p + BWQ * 8);
            const float4 V2 = *(const float4*)(p + BWQ * 8 + 4);
            bcq = make_float4(U1.y, U1.z, U1.w, V1.x);     // b at the output quad
            const float4 Ur = vmax(U0, vmax(U1, U2));
            const float vx = fmaxf(V0.x, fmaxf(V1.x, V2.x));
            const float vy = fmaxf(V0.y, fmaxf(V1.y, V2.y));
            const float t1 = fmaxf(Ur.y, Ur.z);
            const float t2 = fmaxf(Ur.w, vx);
            s2n.x = fmaxf(Ur.x, t1);
            s2n.y = fmaxf(t1, Ur.w);
            s2n.z = fmaxf(Ur.z, t2);
            s2n.w = fmaxf(t2, vy);
        }
        // emit zo = zi-2
        if (s >= 4) {
            const int zo = zi - 2;
            const float4 d = vmax(s2p2, vmax(s2p1, s2n));
            float4 dl;
            dl.x = fmaxf(icp2.x - d.x, 0.f);
            dl.y = fmaxf(icp2.y - d.y, 0.f);
            dl.z = fmaxf(icp2.z - d.z, 0.f);
            dl.w = fmaxf(icp2.w - d.w, 0.f);
            const size_t idx = (size_t)zo * PLANE + (size_t)(y0 + ty) * XD + (x0 + 4 * tx);
            if constexpr (MODE == 0) {
                sth4(skb + idx, dl);              // skel = delta0
                sth4(outb + idx, bcp1);           // a1
            } else {
                const float4 sk = ldh4(skb + idx);
                float4 sv;
                sv.x = sk.x + dl.x * (1.f - sk.x);
                sv.y = sk.y + dl.y * (1.f - sk.y);
                sv.z = sk.z + dl.z * (1.f - sk.z);
                sv.w = sk.w + dl.w * (1.f - sk.w);
                if constexpr (MODE == 1) {
                    sth4(skb + idx, sv);
                    sth4(outb + idx, bcp1);       // a_{k+1}
                } else {
                    float4 w;
                    if (field) {                  // gt skeleton weighted by pred
                        const float4 a = *(const float4*)(lg0 + idx);
                        const float4 b = *(const float4*)(lg1 + idx);
                        w = make_float4(1.f / (1.f + __expf(a.x - b.x)),
                                        1.f / (1.f + __expf(a.y - b.y)),
                                        1.f / (1.f + __expf(a.z - b.z)),
                                        1.f / (1.f + __expf(a.w - b.w)));
                    } else {                      // pred skeleton weighted by gt
                        const int4 t = *(const int4*)(tgb + idx);
                        w = make_float4(t.x == 1 ? 1.f : 0.f, t.y == 1 ? 1.f : 0.f,
                                        t.z == 1 ? 1.f : 0.f, t.w == 1 ? 1.f : 0.f);
                    }
                    sd += sv.x * w.x + sv.y * w.y + sv.z * w.z + sv.w * w.w;
                    ss += sv.x + sv.y + sv.z + sv.w;
                }
            }
        }
        s2p2 = s2p1; s2p1 = s2n;
        icp2 = icp1; icp1 = icq;
        bcp1 = bcq;
    }

    if constexpr (MODE == 2) {
        #pragma unroll
        for (int o = 32; o; o >>= 1) {
            sd += __shfl_down(sd, o, 64);
            ss += __shfl_down(ss, o, 64);
        }
        const int w = tid >> 6;
        if ((tid & 63) == 0) { red[w][0] = sd; red[w][1] = ss; }
        __syncthreads();
        if (tid == 0) {
            float a = 0.f, b = 0.f;
            #pragma unroll
            for (int i = 0; i < 4; ++i) { a += red[i][0]; b += red[i][1]; }
            atomicAdd(&sums[2 * field + 0], a);
            atomicAdd(&sums[2 * field + 1], b);
        }
    }
}

__global__ void final_kernel(const float* __restrict__ sums, float* __restrict__ out)
{
    float tprec = (sums[0] + 1.f) / (sums[1] + 1.f);
    float tsens = (sums[2] + 1.f) / (sums[3] + 1.f);
    float cl = 2.f * tprec * tsens / (tprec + tsens + 1e-7f);
    out[0] = 1.f - cl;
}

extern "C" void kernel_launch(void* const* d_in, const int* in_sizes, int n_in,
                              void* d_out, int out_size, void* d_ws, size_t ws_size,
                              hipStream_t stream)
{
    const float* logits  = (const float*)d_in[0];
    const int*   targets = (const int*)d_in[1];
    float* out  = (float*)d_out;

    float*  sums = (float*)d_ws;
    __half* A    = (__half*)(sums + 16);
    __half* B    = A + NVOL4;
    __half* SK   = B + NVOL4;
    __half* bufs[2] = { A, B };

    hipMemsetAsync(sums, 0, 16 * sizeof(float), stream);

    dim3 g(3 * (YD / YT), ZD / ZCH, 4);    // (36, 12, 4) = 1728 blocks
    dim3 blk(16, 16, 1);

    // k = 0: build a0 inline, skel = delta0, write a1 -> A
    fused_kernel<0><<<g, blk, 0, stream>>>(A, A, SK, logits, targets, sums);
    // k = 1..9: a_k -> a_{k+1}, update skel
    for (int k = 1; k <= 9; ++k) {
        const __half* cin = bufs[(k + 1) & 1];
        __half*       cout = bufs[k & 1];
        fused_kernel<1><<<g, blk, 0, stream>>>(cin, cout, SK, logits, targets, sums);
    }
    // k = 10: read a10 (in B), reduce
    fused_kernel<2><<<g, blk, 0, stream>>>(bufs[1], A, SK, logits, targets, sums);

    final_kernel<<<1, 1, 0, stream>>>(sums, out);
}